// Round 2
// baseline (681.279 us; speedup 1.0000x reference)
//
#include <hip/hip_runtime.h>
#include <math.h>

#define DIM 4096

// One wave (64 threads) per state. Amp index i (12 bits) = lane<<6 | r:
//   lane bits 5..0 = state bits 11..6 (wires 0..5)
//   reg  bits 5..0 = state bits  5..0 (wires 6..11)
// Gates on reg bits: in-register butterflies (pure FMA).
// Gates on lane bits: __shfl_xor partner exchange + sign-adjusted coeffs.
// CNOT chain new[i] = old[i^(i>>1)] done as:
//   (a) per-reg lane gather from sigma(l) = l^(l>>1)
//   (b) swap reg pairs (p, p^32) on odd lanes      (bit5 ^= lane bit0)
//   (c) in-reg swap network realizing r -> r^(r>>1) (stages k=4..0)

__global__ __launch_bounds__(64, 2)
void qsim_kernel(const float* __restrict__ in, const float* __restrict__ params,
                 const float* __restrict__ hw, const float* __restrict__ hb,
                 float* __restrict__ out) {
  __shared__ float4 ga4[36];   // fused RZ@RY@RX per gate: (a.re, a.im, b.re, b.im)
  __shared__ float Btab[64];   // readout coeff, reg-bit part

  const int t = threadIdx.x;   // == lane
  const int b = blockIdx.x;

  // Fused gate matrices M = RZ@RY@RX = [[a,b],[-conj(b),conj(a)]]
  if (t < 36) {
    const float* P = params + t * 3;
    float hx = P[0]*0.5f, hy = P[1]*0.5f, hz = P[2]*0.5f;
    float cx = cosf(hx), sx = sinf(hx);
    float cy = cosf(hy), sy = sinf(hy);
    float cz = cosf(hz), sz = sinf(hz);
    float arr = cy*cx, aii = sy*sx, brr = sy*cx, bii = cy*sx;
    ga4[t] = make_float4(cz*arr + sz*aii,
                         cz*aii - sz*arr,
                         -(cz*brr + sz*bii),
                         -(cz*bii - sz*brr));
  }
  // B(r): reg bit j = state bit j = wire 11-j
  {
    float v = 0.f;
    #pragma unroll
    for (int j = 0; j < 6; ++j) v += hw[11-j] * (((t >> j) & 1) ? -1.f : 1.f);
    Btab[t] = v;
  }
  // A(l): lane bit j = state bit 6+j = wire 5-j
  float Aval = 0.f;
  #pragma unroll
  for (int j = 0; j < 6; ++j) Aval += hw[5-j] * (((t >> j) & 1) ? -1.f : 1.f);

  __syncthreads();

  // ---- load 64 consecutive amps (256B/lane) + normalize ----
  float re[64], im[64];
  const float* inb = in + (size_t)b * DIM + t * 64;
  float ss = 0.f;
  #pragma unroll
  for (int q = 0; q < 16; ++q) {
    float4 v = reinterpret_cast<const float4*>(inb)[q];
    re[4*q+0] = v.x; re[4*q+1] = v.y; re[4*q+2] = v.z; re[4*q+3] = v.w;
    ss += v.x*v.x + v.y*v.y + v.z*v.z + v.w*v.w;
  }
  #pragma unroll
  for (int o = 1; o < 64; o <<= 1) ss += __shfl_xor(ss, o, 64);
  float inv = 1.0f / sqrtf(ss);
  #pragma unroll
  for (int r = 0; r < 64; ++r) { re[r] *= inv; im[r] = 0.f; }

  const int sigma = t ^ (t >> 1);
  const bool l0 = (t & 1) != 0;

  for (int L = 0; L < 3; ++L) {
    // ---- 6 register gates: wires 6..11, reg mask 1<<(11-w) ----
    #pragma unroll
    for (int w = 6; w <= 11; ++w) {
      const int m = 1 << (11 - w);
      float4 g = ga4[L*12 + w];
      float ar = g.x, ai = g.y, br = g.z, bi = g.w;
      #pragma unroll
      for (int p = 0; p < 64; ++p) {
        if (!(p & m)) {
          const int k2 = p | m;
          float v0r = re[p], v0i = im[p], v1r = re[k2], v1i = im[k2];
          re[p]  =  ar*v0r - ai*v0i + br*v1r - bi*v1i;
          im[p]  =  ar*v0i + ai*v0r + br*v1i + bi*v1r;
          re[k2] = -br*v0r - bi*v0i + ar*v1r + ai*v1i;
          im[k2] = -br*v0i + bi*v0r + ar*v1i - ai*v1r;
        }
      }
    }
    // ---- 6 lane gates: wires 0..5, lane mask 1<<(5-w) ----
    #pragma unroll
    for (int w = 0; w <= 5; ++w) {
      const int m = 1 << (5 - w);
      float4 g = ga4[L*12 + w];
      float sgn = (t & m) ? -1.f : 1.f;
      float ar = g.x, cai = sgn*g.y, cbr = sgn*g.z, cbi = g.w;
      #pragma unroll
      for (int p = 0; p < 64; ++p) {
        float pr = __shfl_xor(re[p], m, 64);
        float pi = __shfl_xor(im[p], m, 64);
        float o_r = re[p], o_i = im[p];
        re[p] = ar*o_r - cai*o_i + cbr*pr - cbi*pi;
        im[p] = ar*o_i + cai*o_r + cbr*pi + cbi*pr;
      }
    }
    // ---- CNOT chain: new[i] = old[i ^ (i>>1)] ----
    // (a) lane gather
    #pragma unroll
    for (int p = 0; p < 64; ++p) {
      re[p] = __shfl(re[p], sigma, 64);
      im[p] = __shfl(im[p], sigma, 64);
    }
    // (b) conditional bit5 swap on odd lanes
    #pragma unroll
    for (int p = 0; p < 32; ++p) {
      float a0, a1;
      a0 = re[p]; a1 = re[p+32];
      re[p]    = l0 ? a1 : a0;
      re[p+32] = l0 ? a0 : a1;
      a0 = im[p]; a1 = im[p+32];
      im[p]    = l0 ? a1 : a0;
      im[p+32] = l0 ? a0 : a1;
    }
    // (c) swap network: stages k=4..0, swap (p, p^(1<<k)) where bit k+1 set
    #pragma unroll
    for (int k = 4; k >= 0; --k) {
      const int mk = 1 << k;
      #pragma unroll
      for (int p = 0; p < 64; ++p) {
        if ((p & (mk << 1)) && !(p & mk)) {
          float tmp;
          tmp = re[p]; re[p] = re[p|mk]; re[p|mk] = tmp;
          tmp = im[p]; im[p] = im[p|mk]; im[p|mk] = tmp;
        }
      }
    }
  }

  // ---- readout: sum |amp|^2 * (A(lane) + B(reg)) ----
  float sA = 0.f, sB = 0.f;
  const float4* Bt4 = reinterpret_cast<const float4*>(Btab);
  #pragma unroll
  for (int q = 0; q < 16; ++q) {
    float4 bt = Bt4[q];
    float p0 = re[4*q+0]*re[4*q+0] + im[4*q+0]*im[4*q+0];
    float p1 = re[4*q+1]*re[4*q+1] + im[4*q+1]*im[4*q+1];
    float p2 = re[4*q+2]*re[4*q+2] + im[4*q+2]*im[4*q+2];
    float p3 = re[4*q+3]*re[4*q+3] + im[4*q+3]*im[4*q+3];
    sA += p0 + p1 + p2 + p3;
    sB += p0*bt.x + p1*bt.y + p2*bt.z + p3*bt.w;
  }
  float res = Aval * sA + sB;
  #pragma unroll
  for (int o = 1; o < 64; o <<= 1) res += __shfl_xor(res, o, 64);
  if (t == 0) out[b] = res + hb[0];
}

extern "C" void kernel_launch(void* const* d_in, const int* in_sizes, int n_in,
                              void* d_out, int out_size, void* d_ws, size_t ws_size,
                              hipStream_t stream) {
  const float* st     = (const float*)d_in[0];
  const float* params = (const float*)d_in[1];
  const float* hwp    = (const float*)d_in[2];
  const float* hbp    = (const float*)d_in[3];
  float* outp = (float*)d_out;
  int batch = in_sizes[0] / DIM;
  qsim_kernel<<<batch, 64, 0, stream>>>(st, params, hwp, hbp, outp);
}

// Round 3
// 127.448 us; speedup vs baseline: 5.3456x; 5.3456x over previous
//
#include <hip/hip_runtime.h>
#include <math.h>

#define DIM 4096

// 256 threads/block (4 waves), one block per state. Amp index i = t*16 + j:
//   j bits 3..0  = i bits 3..0  = wires 8..11  -> in-register butterflies
//   lane bits    = i bits 9..4  = wires 2..7   -> __shfl_xor gates
//   wave bits    = i bits 11..10= wires 0..1   -> fused into LDS 4-partner
//                                                gather together with the
//                                                CNOT chain sigma(i)=i^(i>>1)
// LDS slot swizzle S(i) = i ^ ((i>>4)&15): both the linear write and the
// sigma-gather read hit the 4-cycle b64 floor (rank-4 lane->slot%16 maps).

__global__ __launch_bounds__(256, 3)
void qsim_kernel(const float* __restrict__ in, const float* __restrict__ params,
                 const float* __restrict__ hw, const float* __restrict__ hb,
                 float* __restrict__ out) {
  __shared__ float2 st2[DIM];    // 32 KB: (re, im) per amplitude
  __shared__ float4 ga4[36];     // fused RZ@RY@RX: (a.re, a.im, b.re, b.im)
  __shared__ float red[4];

  const int t = threadIdx.x;
  const int b = blockIdx.x;

  // Fused gate matrices M = RZ@RY@RX = [[a,b],[-conj(b),conj(a)]]
  if (t < 36) {
    const float* P = params + t * 3;
    float hx = P[0]*0.5f, hy = P[1]*0.5f, hz = P[2]*0.5f;
    float cx = cosf(hx), sx = sinf(hx);
    float cy = cosf(hy), sy = sinf(hy);
    float cz = cosf(hz), sz = sinf(hz);
    float arr = cy*cx, aii = sy*sx, brr = sy*cx, bii = cy*sx;
    ga4[t] = make_float4(cz*arr + sz*aii,
                         cz*aii - sz*arr,
                         -(cz*brr + sz*bii),
                         -(cz*bii - sz*brr));
  }

  // ---- load 16 consecutive amps + block-wide norm ----
  float re[16], im[16];
  const float* inb = in + (size_t)b * DIM + t * 16;
  float ss = 0.f;
  #pragma unroll
  for (int q = 0; q < 4; ++q) {
    float4 v = reinterpret_cast<const float4*>(inb)[q];
    re[4*q+0]=v.x; re[4*q+1]=v.y; re[4*q+2]=v.z; re[4*q+3]=v.w;
    ss += v.x*v.x + v.y*v.y + v.z*v.z + v.w*v.w;
  }
  #pragma unroll
  for (int o = 1; o < 64; o <<= 1) ss += __shfl_xor(ss, o, 64);
  if ((t & 63) == 0) red[t >> 6] = ss;
  __syncthreads();               // also publishes ga4
  float inv = 1.0f / sqrtf(red[0] + red[1] + red[2] + red[3]);
  #pragma unroll
  for (int j = 0; j < 16; ++j) { re[j] *= inv; im[j] = 0.f; }

  // thread-constant addressing
  const int wbase = (t << 4) ^ (t & 15);            // S(t*16 + j) = wbase ^ j
  const int sigt  = (t << 4) ^ (t << 3);            // thread part of sigma(i)
  const int gb    = (sigt ^ ((sigt >> 4) & 15)) & 1023;  // S(sigt), bits 11..10 cleared
  const int x11   = (t >> 7) & 1;                   // sigma(i) bit 11 (wire 0)
  const int x10   = ((t >> 6) ^ (t >> 7)) & 1;      // sigma(i) bit 10 (wire 1)

  for (int L = 0; L < 3; ++L) {
    // ---- 4 register gates: wires 8..11, mask on j ----
    #pragma unroll
    for (int w = 8; w <= 11; ++w) {
      const int m = 1 << (11 - w);
      float4 g = ga4[L*12 + w];
      float ar = g.x, ai = g.y, br = g.z, bi = g.w;
      #pragma unroll
      for (int p = 0; p < 16; ++p) {
        if (!(p & m)) {
          const int k2 = p | m;
          float v0r = re[p], v0i = im[p], v1r = re[k2], v1i = im[k2];
          re[p]  =  ar*v0r - ai*v0i + br*v1r - bi*v1i;
          im[p]  =  ar*v0i + ai*v0r + br*v1i + bi*v1r;
          re[k2] = -br*v0r - bi*v0i + ar*v1r + ai*v1i;
          im[k2] = -br*v0i + bi*v0r + ar*v1i - ai*v1r;
        }
      }
    }
    // ---- 6 lane gates: wires 2..7, lane mask 1<<(7-w) ----
    #pragma unroll
    for (int w = 2; w <= 7; ++w) {
      const int m = 1 << (7 - w);
      float4 g = ga4[L*12 + w];
      float sgn = (t & m) ? -1.f : 1.f;
      float ar = g.x, cai = sgn*g.y, cbr = sgn*g.z, cbi = g.w;
      #pragma unroll
      for (int p = 0; p < 16; ++p) {
        float pr = __shfl_xor(re[p], m, 64);
        float pi = __shfl_xor(im[p], m, 64);
        float o_r = re[p], o_i = im[p];
        re[p] = ar*o_r - cai*o_i + cbr*pr - cbi*pi;
        im[p] = ar*o_i + cai*o_r + cbr*pi + cbi*pr;
      }
    }
    // ---- write post-(wires 2..11) state ----
    #pragma unroll
    for (int j = 0; j < 16; ++j) st2[wbase ^ j] = make_float2(re[j], im[j]);
    __syncthreads();

    // ---- fused: wave gates (wires 0,1) + CNOT chain, via 4-partner gather ----
    // new[i] = sum_y G0[x11][y>>1] * G1[x10][y&1] * mid[sigma(i) w/ bits11,10 := y]
    float4 g0 = ga4[L*12 + 0], g1 = ga4[L*12 + 1];
    float u0r, u0i, u1r, u1i, v0r, v0i, v1r, v1i;
    if (x11) { u0r = -g0.z; u0i = g0.w; u1r = g0.x; u1i = -g0.y; }
    else     { u0r =  g0.x; u0i = g0.y; u1r = g0.z; u1i =  g0.w; }
    if (x10) { v0r = -g1.z; v0i = g1.w; v1r = g1.x; v1i = -g1.y; }
    else     { v0r =  g1.x; v0i = g1.y; v1r = g1.z; v1i =  g1.w; }
    float c0r = u0r*v0r - u0i*v0i, c0i = u0r*v0i + u0i*v0r;
    float c1r = u0r*v1r - u0i*v1i, c1i = u0r*v1i + u0i*v1r;
    float c2r = u1r*v0r - u1i*v0i, c2i = u1r*v0i + u1i*v0r;
    float c3r = u1r*v1r - u1i*v1i, c3i = u1r*v1i + u1i*v1r;
    #pragma unroll
    for (int j = 0; j < 16; ++j) {
      const int base = gb ^ (j ^ (j >> 1));
      float2 m0 = st2[base];
      float2 m1 = st2[base + 1024];
      float2 m2 = st2[base + 2048];
      float2 m3 = st2[base + 3072];
      re[j] = c0r*m0.x - c0i*m0.y + c1r*m1.x - c1i*m1.y
            + c2r*m2.x - c2i*m2.y + c3r*m3.x - c3i*m3.y;
      im[j] = c0r*m0.y + c0i*m0.x + c1r*m1.y + c1i*m1.x
            + c2r*m2.y + c2i*m2.x + c3r*m3.y + c3i*m3.x;
    }
    __syncthreads();   // all gathers done before next layer's write
  }

  // ---- readout: sum |amp|^2 * c(i), i = t*16 + j (regs hold final state) ----
  float Ct = 0.f;
  #pragma unroll
  for (int p = 0; p < 8; ++p) Ct += hw[7-p] * (((t >> p) & 1) ? -1.f : 1.f);
  float h11 = hw[11], h10 = hw[10], h9 = hw[9], h8 = hw[8];
  float acc = 0.f;
  #pragma unroll
  for (int j = 0; j < 16; ++j) {
    float pj = re[j]*re[j] + im[j]*im[j];
    float cj = ((j&1) ? -h11 : h11) + ((j&2) ? -h10 : h10)
             + ((j&4) ? -h9  : h9 ) + ((j&8) ? -h8  : h8 );
    acc += pj * (Ct + cj);
  }
  #pragma unroll
  for (int o = 1; o < 64; o <<= 1) acc += __shfl_xor(acc, o, 64);
  if ((t & 63) == 0) red[t >> 6] = acc;
  __syncthreads();
  if (t == 0) out[b] = red[0] + red[1] + red[2] + red[3] + hb[0];
}

extern "C" void kernel_launch(void* const* d_in, const int* in_sizes, int n_in,
                              void* d_out, int out_size, void* d_ws, size_t ws_size,
                              hipStream_t stream) {
  const float* st     = (const float*)d_in[0];
  const float* params = (const float*)d_in[1];
  const float* hwp    = (const float*)d_in[2];
  const float* hbp    = (const float*)d_in[3];
  float* outp = (float*)d_out;
  int batch = in_sizes[0] / DIM;
  qsim_kernel<<<batch, 256, 0, stream>>>(st, params, hwp, hbp, outp);
}

// Round 4
// 125.205 us; speedup vs baseline: 5.4413x; 1.0179x over previous
//
#include <hip/hip_runtime.h>
#include <math.h>

#define DIM 4096

// 256 threads/block (4 waves), one block per state. Amp index i = t*16 + j:
//   j bits 3..0   = i bits 3..0   = wires 8..11 -> in-register butterflies
//   lane bits     = i bits 9..4   = wires 2..7  -> __shfl_xor gates
//   wave bits     = i bits 11..10 = wires 0..1  -> fused with CNOT chain
//                                   sigma(i)=i^(i>>1) into one LDS 4-partner gather
// LDS slot swizzle: S(i) = i ^ h4((i>>4)&15), h4(x) = x^(x>>1)^(x>>2)^(x>>3).
// h4 = inverse of the Gray map g(l)=l^(l>>1), so BOTH the linear write
// (bank-pair = j ^ h4(l), bijective) and the sigma-gather read
// (bank-pair = 8*l0 ^ l, bijective) hit the b64 4-cycle floor.

__device__ __forceinline__ int h4(int x) {
  return (x ^ (x >> 1) ^ (x >> 2) ^ (x >> 3)) & 15;
}

__global__ __launch_bounds__(256)
void qsim_kernel(const float* __restrict__ in, const float* __restrict__ params,
                 const float* __restrict__ hw, const float* __restrict__ hb,
                 float* __restrict__ out) {
  __shared__ float2 st2[DIM];    // 32 KB: (re, im) per amplitude, swizzled slots
  __shared__ float4 ga4[36];     // fused RZ@RY@RX: (a.re, a.im, b.re, b.im)
  __shared__ float red[4];

  const int t = threadIdx.x;
  const int b = blockIdx.x;

  // Fused gate matrices M = RZ@RY@RX = [[a,b],[-conj(b),conj(a)]]
  if (t < 36) {
    const float* P = params + t * 3;
    float hx = P[0]*0.5f, hy = P[1]*0.5f, hz = P[2]*0.5f;
    float cx = cosf(hx), sx = sinf(hx);
    float cy = cosf(hy), sy = sinf(hy);
    float cz = cosf(hz), sz = sinf(hz);
    float arr = cy*cx, aii = sy*sx, brr = sy*cx, bii = cy*sx;
    ga4[t] = make_float4(cz*arr + sz*aii,
                         cz*aii - sz*arr,
                         -(cz*brr + sz*bii),
                         -(cz*bii - sz*brr));
  }

  // ---- load 16 consecutive amps + block-wide norm ----
  float re[16], im[16];
  const float* inb = in + (size_t)b * DIM + t * 16;
  float ss = 0.f;
  #pragma unroll
  for (int q = 0; q < 4; ++q) {
    float4 v = reinterpret_cast<const float4*>(inb)[q];
    re[4*q+0]=v.x; re[4*q+1]=v.y; re[4*q+2]=v.z; re[4*q+3]=v.w;
    ss += v.x*v.x + v.y*v.y + v.z*v.z + v.w*v.w;
  }
  #pragma unroll
  for (int o = 1; o < 64; o <<= 1) ss += __shfl_xor(ss, o, 64);
  if ((t & 63) == 0) red[t >> 6] = ss;
  __syncthreads();               // also publishes ga4
  float inv = 1.0f / sqrtf(red[0] + red[1] + red[2] + red[3]);
  #pragma unroll
  for (int j = 0; j < 16; ++j) { re[j] *= inv; im[j] = 0.f; }

  // thread-constant addressing (all GF(2)-linear in i)
  const int wbase = (t << 4) ^ h4(t & 15);          // write slot = wbase ^ j
  const int sig   = (t << 4) ^ (t << 3);            // sigma(i) thread part
  const int sigc  = sig & 1023;                     // bits 11,10 cleared
  const int gb    = sigc ^ h4((sigc >> 4) & 15);    // gather slot = gb ^ g(j) + y*1024
  const int x11   = (t >> 7) & 1;                   // sigma(i) bit 11 (wire 0)
  const int x10   = ((t >> 6) ^ (t >> 7)) & 1;      // sigma(i) bit 10 (wire 1)

  for (int L = 0; L < 3; ++L) {
    // ---- 4 register gates: wires 8..11, mask on j ----
    #pragma unroll
    for (int w = 8; w <= 11; ++w) {
      const int m = 1 << (11 - w);
      float4 g = ga4[L*12 + w];
      float ar = g.x, ai = g.y, br = g.z, bi = g.w;
      #pragma unroll
      for (int p = 0; p < 16; ++p) {
        if (!(p & m)) {
          const int k2 = p | m;
          float v0r = re[p], v0i = im[p], v1r = re[k2], v1i = im[k2];
          re[p]  =  ar*v0r - ai*v0i + br*v1r - bi*v1i;
          im[p]  =  ar*v0i + ai*v0r + br*v1i + bi*v1r;
          re[k2] = -br*v0r - bi*v0i + ar*v1r + ai*v1i;
          im[k2] = -br*v0i + bi*v0r + ar*v1i - ai*v1r;
        }
      }
    }
    // ---- 6 lane gates: wires 2..7, lane mask 1<<(7-w) ----
    #pragma unroll
    for (int w = 2; w <= 7; ++w) {
      const int m = 1 << (7 - w);
      float4 g = ga4[L*12 + w];
      float sgn = (t & m) ? -1.f : 1.f;
      float ar = g.x, cai = sgn*g.y, cbr = sgn*g.z, cbi = g.w;
      #pragma unroll
      for (int p = 0; p < 16; ++p) {
        float pr = __shfl_xor(re[p], m, 64);
        float pi = __shfl_xor(im[p], m, 64);
        float o_r = re[p], o_i = im[p];
        re[p] = ar*o_r - cai*o_i + cbr*pr - cbi*pi;
        im[p] = ar*o_i + cai*o_r + cbr*pi + cbi*pr;
      }
    }
    // ---- write post-(wires 2..11) state (conflict-free swizzled) ----
    #pragma unroll
    for (int j = 0; j < 16; ++j) st2[wbase ^ j] = make_float2(re[j], im[j]);
    __syncthreads();

    // ---- fused: wave gates (wires 0,1) + CNOT chain, via 4-partner gather ----
    // new[i] = sum_y G0[x11][y>>1]*G1[x10][y&1] * mid[sigma(i) w/ bits11,10 := y]
    float4 g0 = ga4[L*12 + 0], g1 = ga4[L*12 + 1];
    float u0r, u0i, u1r, u1i, v0r, v0i, v1r, v1i;
    if (x11) { u0r = -g0.z; u0i = g0.w; u1r = g0.x; u1i = -g0.y; }
    else     { u0r =  g0.x; u0i = g0.y; u1r = g0.z; u1i =  g0.w; }
    if (x10) { v0r = -g1.z; v0i = g1.w; v1r = g1.x; v1i = -g1.y; }
    else     { v0r =  g1.x; v0i = g1.y; v1r = g1.z; v1i =  g1.w; }
    float c0r = u0r*v0r - u0i*v0i, c0i = u0r*v0i + u0i*v0r;
    float c1r = u0r*v1r - u0i*v1i, c1i = u0r*v1i + u0i*v1r;
    float c2r = u1r*v0r - u1i*v0i, c2i = u1r*v0i + u1i*v0r;
    float c3r = u1r*v1r - u1i*v1i, c3i = u1r*v1i + u1i*v1r;
    #pragma unroll
    for (int j = 0; j < 16; ++j) {
      const int base = gb ^ (j ^ (j >> 1));
      float2 m0 = st2[base];
      float2 m1 = st2[base + 1024];
      float2 m2 = st2[base + 2048];
      float2 m3 = st2[base + 3072];
      re[j] = c0r*m0.x - c0i*m0.y + c1r*m1.x - c1i*m1.y
            + c2r*m2.x - c2i*m2.y + c3r*m3.x - c3i*m3.y;
      im[j] = c0r*m0.y + c0i*m0.x + c1r*m1.y + c1i*m1.x
            + c2r*m2.y + c2i*m2.x + c3r*m3.y + c3i*m3.x;
    }
    __syncthreads();   // all gathers done before next layer's write
  }

  // ---- readout: sum |amp|^2 * c(i), i = t*16 + j (regs hold final state) ----
  float Ct = 0.f;
  #pragma unroll
  for (int p = 0; p < 8; ++p) Ct += hw[7-p] * (((t >> p) & 1) ? -1.f : 1.f);
  float h11 = hw[11], h10 = hw[10], h9 = hw[9], h8 = hw[8];
  float acc = 0.f;
  #pragma unroll
  for (int j = 0; j < 16; ++j) {
    float pj = re[j]*re[j] + im[j]*im[j];
    float cj = ((j&1) ? -h11 : h11) + ((j&2) ? -h10 : h10)
             + ((j&4) ? -h9  : h9 ) + ((j&8) ? -h8  : h8 );
    acc += pj * (Ct + cj);
  }
  #pragma unroll
  for (int o = 1; o < 64; o <<= 1) acc += __shfl_xor(acc, o, 64);
  if ((t & 63) == 0) red[t >> 6] = acc;
  __syncthreads();
  if (t == 0) out[b] = red[0] + red[1] + red[2] + red[3] + hb[0];
}

extern "C" void kernel_launch(void* const* d_in, const int* in_sizes, int n_in,
                              void* d_out, int out_size, void* d_ws, size_t ws_size,
                              hipStream_t stream) {
  const float* st     = (const float*)d_in[0];
  const float* params = (const float*)d_in[1];
  const float* hwp    = (const float*)d_in[2];
  const float* hbp    = (const float*)d_in[3];
  float* outp = (float*)d_out;
  int batch = in_sizes[0] / DIM;
  qsim_kernel<<<batch, 256, 0, stream>>>(st, params, hwp, hbp, outp);
}

// Round 6
// 119.881 us; speedup vs baseline: 5.6829x; 1.0444x over previous
//
#include <hip/hip_runtime.h>
#include <math.h>

#define DIM 4096

// 256 threads/block (4 waves), one block per state. Amp index i = t*16 + j:
//   j bits 3..0   = i bits 3..0   = wires 8..11 -> in-register butterflies
//   lane bits     = i bits 9..4   = wires 2..7  -> VALU cross-lane gates
//                                   (DPP quad_perm / row shifts / row_ror /
//                                    permlane16_swap / permlane32_swap)
//   wave bits     = i bits 11..10 = wires 0..1  -> fused with CNOT chain
//                                   sigma(i)=i^(i>>1) into one LDS 4-partner gather
// LDS slot swizzle: S(i) = i ^ h4((i>>4)&15), h4 = inverse Gray map, makes both
// the linear write and the sigma-gather read bank-conflict-free (verified: 0).
//
// DPP semantics (GPUOpen cross-lane doc): row_shr:N -> result[i]=src[i-N],
// row_shl:N -> result[i]=src[i+N], shifts confined to 16-lane rows.
// permlaneK_swap(a,b) -> {a',b'}: a' odd-K-blocks := b even-K-blocks and
// b' even-K-blocks := a odd-K-blocks; with a=b=x the partner value lands in
// r[0] for hi lanes and r[1] for lo lanes.

__device__ __forceinline__ int h4(int x) {
  return (x ^ (x >> 1) ^ (x >> 2) ^ (x >> 3)) & 15;
}

// Cross-lane exchange of x with lane^M partner, entirely on the VALU pipe.
template<int M>
__device__ __forceinline__ float xch(float x, bool hi) {
  int xi = __float_as_int(x);
  if constexpr (M == 1) {        // quad_perm [1,0,3,2]
    return __int_as_float(__builtin_amdgcn_mov_dpp(xi, 0xB1, 0xF, 0xF, false));
  } else if constexpr (M == 2) { // quad_perm [2,3,0,1]
    return __int_as_float(__builtin_amdgcn_mov_dpp(xi, 0x4E, 0xF, 0xF, false));
  } else if constexpr (M == 4) {
    // banks 0,2 (lanes 0-3,8-11) need src[i+4] -> row_shl:4 (0x104)
    // banks 1,3 (lanes 4-7,12-15) need src[i-4] -> row_shr:4 (0x114)
    int r = __builtin_amdgcn_update_dpp(xi, xi, 0x104, 0xF, 0x5, false);
    r     = __builtin_amdgcn_update_dpp(r,  xi, 0x114, 0xF, 0xA, false);
    return __int_as_float(r);
  } else if constexpr (M == 8) { // row_ror:8 == xor 8 within 16-lane row
    return __int_as_float(__builtin_amdgcn_mov_dpp(xi, 0x128, 0xF, 0xF, false));
  } else if constexpr (M == 16) {
#if __has_builtin(__builtin_amdgcn_permlane16_swap)
    auto r = __builtin_amdgcn_permlane16_swap(xi, xi, false, false);
    return __int_as_float(hi ? r[0] : r[1]);   // partner value: see header note
#else
    return __int_as_float(__builtin_amdgcn_ds_swizzle(xi, 0x401F));
#endif
  } else {                       // M == 32
#if __has_builtin(__builtin_amdgcn_permlane32_swap)
    auto r = __builtin_amdgcn_permlane32_swap(xi, xi, false, false);
    return __int_as_float(hi ? r[0] : r[1]);
#else
    return __shfl_xor(x, 32, 64);
#endif
  }
}

template<int M>
__device__ __forceinline__ void lane_gate(float4 g, int t,
                                          float* __restrict__ re,
                                          float* __restrict__ im) {
  const bool hi = (t & M) != 0;
  const float sgn = hi ? -1.f : 1.f;
  const float ar = g.x, cai = sgn * g.y, cbr = sgn * g.z, cbi = g.w;
  #pragma unroll
  for (int p = 0; p < 16; ++p) {
    float pr = xch<M>(re[p], hi);
    float pi = xch<M>(im[p], hi);
    float o_r = re[p], o_i = im[p];
    re[p] = ar*o_r - cai*o_i + cbr*pr - cbi*pi;
    im[p] = ar*o_i + cai*o_r + cbr*pi + cbi*pr;
  }
}

__global__ __launch_bounds__(256)
void qsim_kernel(const float* __restrict__ in, const float* __restrict__ params,
                 const float* __restrict__ hw, const float* __restrict__ hb,
                 float* __restrict__ out) {
  __shared__ float2 st2[DIM];    // 32 KB: (re, im) per amplitude, swizzled slots
  __shared__ float4 ga4[36];     // fused RZ@RY@RX: (a.re, a.im, b.re, b.im)
  __shared__ float red[4];

  const int t = threadIdx.x;
  const int b = blockIdx.x;

  // Fused gate matrices M = RZ@RY@RX = [[a,b],[-conj(b),conj(a)]]
  if (t < 36) {
    const float* P = params + t * 3;
    float hx = P[0]*0.5f, hy = P[1]*0.5f, hz = P[2]*0.5f;
    float cx = cosf(hx), sx = sinf(hx);
    float cy = cosf(hy), sy = sinf(hy);
    float cz = cosf(hz), sz = sinf(hz);
    float arr = cy*cx, aii = sy*sx, brr = sy*cx, bii = cy*sx;
    ga4[t] = make_float4(cz*arr + sz*aii,
                         cz*aii - sz*arr,
                         -(cz*brr + sz*bii),
                         -(cz*bii - sz*brr));
  }

  // ---- load 16 consecutive amps + block-wide norm ----
  float re[16], im[16];
  const float* inb = in + (size_t)b * DIM + t * 16;
  float ss = 0.f;
  #pragma unroll
  for (int q = 0; q < 4; ++q) {
    float4 v = reinterpret_cast<const float4*>(inb)[q];
    re[4*q+0]=v.x; re[4*q+1]=v.y; re[4*q+2]=v.z; re[4*q+3]=v.w;
    ss += v.x*v.x + v.y*v.y + v.z*v.z + v.w*v.w;
  }
  #pragma unroll
  for (int o = 1; o < 64; o <<= 1) ss += __shfl_xor(ss, o, 64);
  if ((t & 63) == 0) red[t >> 6] = ss;
  __syncthreads();               // also publishes ga4
  float inv = 1.0f / sqrtf(red[0] + red[1] + red[2] + red[3]);
  #pragma unroll
  for (int j = 0; j < 16; ++j) { re[j] *= inv; im[j] = 0.f; }

  // thread-constant addressing (all GF(2)-linear in i)
  const int wbase = (t << 4) ^ h4(t & 15);          // write slot = wbase ^ j
  const int sig   = (t << 4) ^ (t << 3);            // sigma(i) thread part
  const int sigc  = sig & 1023;                     // bits 11,10 cleared
  const int gb    = sigc ^ h4((sigc >> 4) & 15);    // gather slot = gb ^ g(j) + y*1024
  const int x11   = (t >> 7) & 1;                   // sigma(i) bit 11 (wire 0)
  const int x10   = ((t >> 6) ^ (t >> 7)) & 1;      // sigma(i) bit 10 (wire 1)

  for (int L = 0; L < 3; ++L) {
    // ---- 4 register gates: wires 8..11, mask on j ----
    #pragma unroll
    for (int w = 8; w <= 11; ++w) {
      const int m = 1 << (11 - w);
      float4 g = ga4[L*12 + w];
      float ar = g.x, ai = g.y, br = g.z, bi = g.w;
      #pragma unroll
      for (int p = 0; p < 16; ++p) {
        if (!(p & m)) {
          const int k2 = p | m;
          float v0r = re[p], v0i = im[p], v1r = re[k2], v1i = im[k2];
          re[p]  =  ar*v0r - ai*v0i + br*v1r - bi*v1i;
          im[p]  =  ar*v0i + ai*v0r + br*v1i + bi*v1r;
          re[k2] = -br*v0r - bi*v0i + ar*v1r + ai*v1i;
          im[k2] = -br*v0i + bi*v0r + ar*v1i - ai*v1r;
        }
      }
    }
    // ---- 6 lane gates: wires 2..7 -> masks 32,16,8,4,2,1 (all VALU) ----
    lane_gate<32>(ga4[L*12 + 2], t, re, im);
    lane_gate<16>(ga4[L*12 + 3], t, re, im);
    lane_gate< 8>(ga4[L*12 + 4], t, re, im);
    lane_gate< 4>(ga4[L*12 + 5], t, re, im);
    lane_gate< 2>(ga4[L*12 + 6], t, re, im);
    lane_gate< 1>(ga4[L*12 + 7], t, re, im);

    // ---- write post-(wires 2..11) state (conflict-free swizzled) ----
    #pragma unroll
    for (int j = 0; j < 16; ++j) st2[wbase ^ j] = make_float2(re[j], im[j]);
    __syncthreads();

    // ---- fused: wave gates (wires 0,1) + CNOT chain, via 4-partner gather ----
    // new[i] = sum_y G0[x11][y>>1]*G1[x10][y&1] * mid[sigma(i) w/ bits11,10 := y]
    float4 g0 = ga4[L*12 + 0], g1 = ga4[L*12 + 1];
    float u0r, u0i, u1r, u1i, v0r, v0i, v1r, v1i;
    if (x11) { u0r = -g0.z; u0i = g0.w; u1r = g0.x; u1i = -g0.y; }
    else     { u0r =  g0.x; u0i = g0.y; u1r = g0.z; u1i =  g0.w; }
    if (x10) { v0r = -g1.z; v0i = g1.w; v1r = g1.x; v1i = -g1.y; }
    else     { v0r =  g1.x; v0i = g1.y; v1r = g1.z; v1i =  g1.w; }
    float c0r = u0r*v0r - u0i*v0i, c0i = u0r*v0i + u0i*v0r;
    float c1r = u0r*v1r - u0i*v1i, c1i = u0r*v1i + u0i*v1r;
    float c2r = u1r*v0r - u1i*v0i, c2i = u1r*v0i + u1i*v0r;
    float c3r = u1r*v1r - u1i*v1i, c3i = u1r*v1i + u1i*v1r;
    #pragma unroll
    for (int j = 0; j < 16; ++j) {
      const int base = gb ^ (j ^ (j >> 1));
      float2 m0 = st2[base];
      float2 m1 = st2[base + 1024];
      float2 m2 = st2[base + 2048];
      float2 m3 = st2[base + 3072];
      re[j] = c0r*m0.x - c0i*m0.y + c1r*m1.x - c1i*m1.y
            + c2r*m2.x - c2i*m2.y + c3r*m3.x - c3i*m3.y;
      im[j] = c0r*m0.y + c0i*m0.x + c1r*m1.y + c1i*m1.x
            + c2r*m2.y + c2i*m2.x + c3r*m3.y + c3i*m3.x;
    }
    __syncthreads();   // all gathers done before next layer's write
  }

  // ---- readout: sum |amp|^2 * c(i), i = t*16 + j (regs hold final state) ----
  float Ct = 0.f;
  #pragma unroll
  for (int p = 0; p < 8; ++p) Ct += hw[7-p] * (((t >> p) & 1) ? -1.f : 1.f);
  float h11 = hw[11], h10 = hw[10], h9 = hw[9], h8 = hw[8];
  float acc = 0.f;
  #pragma unroll
  for (int j = 0; j < 16; ++j) {
    float pj = re[j]*re[j] + im[j]*im[j];
    float cj = ((j&1) ? -h11 : h11) + ((j&2) ? -h10 : h10)
             + ((j&4) ? -h9  : h9 ) + ((j&8) ? -h8  : h8 );
    acc += pj * (Ct + cj);
  }
  #pragma unroll
  for (int o = 1; o < 64; o <<= 1) acc += __shfl_xor(acc, o, 64);
  if ((t & 63) == 0) red[t >> 6] = acc;
  __syncthreads();
  if (t == 0) out[b] = red[0] + red[1] + red[2] + red[3] + hb[0];
}

extern "C" void kernel_launch(void* const* d_in, const int* in_sizes, int n_in,
                              void* d_out, int out_size, void* d_ws, size_t ws_size,
                              hipStream_t stream) {
  const float* st     = (const float*)d_in[0];
  const float* params = (const float*)d_in[1];
  const float* hwp    = (const float*)d_in[2];
  const float* hbp    = (const float*)d_in[3];
  float* outp = (float*)d_out;
  int batch = in_sizes[0] / DIM;
  qsim_kernel<<<batch, 256, 0, stream>>>(st, params, hwp, hbp, outp);
}

// Round 7
// 115.012 us; speedup vs baseline: 5.9235x; 1.0423x over previous
//
#include <hip/hip_runtime.h>
#include <math.h>

#define DIM 4096

// 256 threads/block (4 waves), one block per state. Amp index i = t*16 + j:
//   j bits 3..0   = i bits 3..0   = wires 8..11 -> in-register butterflies
//   lane bits     = i bits 9..4   = wires 2..7  -> cross-lane gates:
//       masks 1,2,8 -> 1 DPP op; mask 4 -> 2 DPP ops (VALU pipe)
//       masks 16,32 -> ds_swizzle / ds_bpermute (DS crossbar pipe, 1 op,
//                      no select needed) -- pipe balance: VALU is the
//                      bottleneck (82% busy), DS is nearly idle.
//   wave bits     = i bits 11..10 = wires 0..1  -> fused with CNOT chain
//                                   sigma(i)=i^(i>>1) into one LDS 4-partner gather
// LDS slot swizzle: S(i) = i ^ h4((i>>4)&15), h4 = inverse Gray map, makes both
// the linear write and the sigma-gather read bank-conflict-free (verified: 0).

__device__ __forceinline__ int h4(int x) {
  return (x ^ (x >> 1) ^ (x >> 2) ^ (x >> 3)) & 15;
}

// Cross-lane exchange of x with lane^M partner.
// paddr: precomputed ds_bpermute byte address of partner (used by M==32 only).
template<int M>
__device__ __forceinline__ float xch(float x, int paddr) {
  int xi = __float_as_int(x);
  if constexpr (M == 1) {        // quad_perm [1,0,3,2]
    return __int_as_float(__builtin_amdgcn_mov_dpp(xi, 0xB1, 0xF, 0xF, false));
  } else if constexpr (M == 2) { // quad_perm [2,3,0,1]
    return __int_as_float(__builtin_amdgcn_mov_dpp(xi, 0x4E, 0xF, 0xF, false));
  } else if constexpr (M == 4) {
    // banks 0,2 (lanes 0-3,8-11) need src[i+4] -> row_shl:4 (0x104)
    // banks 1,3 (lanes 4-7,12-15) need src[i-4] -> row_shr:4 (0x114)
    int r = __builtin_amdgcn_update_dpp(xi, xi, 0x104, 0xF, 0x5, false);
    r     = __builtin_amdgcn_update_dpp(r,  xi, 0x114, 0xF, 0xA, false);
    return __int_as_float(r);
  } else if constexpr (M == 8) { // row_ror:8 == xor 8 within 16-lane row
    return __int_as_float(__builtin_amdgcn_mov_dpp(xi, 0x128, 0xF, 0xF, false));
  } else if constexpr (M == 16) { // xor-16 via LDS crossbar (BitMode)
    return __int_as_float(__builtin_amdgcn_ds_swizzle(xi, 0x401F));
  } else {                       // M == 32: cross-half via bpermute
    return __int_as_float(__builtin_amdgcn_ds_bpermute(paddr, xi));
  }
}

template<int M>
__device__ __forceinline__ void lane_gate(float4 g, int t, int paddr,
                                          float* __restrict__ re,
                                          float* __restrict__ im) {
  const bool hi = (t & M) != 0;
  const float sgn = hi ? -1.f : 1.f;
  const float ar = g.x, cai = sgn * g.y, cbr = sgn * g.z, cbi = g.w;
  #pragma unroll
  for (int p = 0; p < 16; ++p) {
    float pr = xch<M>(re[p], paddr);
    float pi = xch<M>(im[p], paddr);
    float o_r = re[p], o_i = im[p];
    re[p] = ar*o_r - cai*o_i + cbr*pr - cbi*pi;
    im[p] = ar*o_i + cai*o_r + cbr*pi + cbi*pr;
  }
}

__global__ __launch_bounds__(256)
void qsim_kernel(const float* __restrict__ in, const float* __restrict__ params,
                 const float* __restrict__ hw, const float* __restrict__ hb,
                 float* __restrict__ out) {
  __shared__ float2 st2[DIM];    // 32 KB: (re, im) per amplitude, swizzled slots
  __shared__ float4 ga4[36];     // fused RZ@RY@RX: (a.re, a.im, b.re, b.im)
  __shared__ float red[4];

  const int t = threadIdx.x;
  const int b = blockIdx.x;

  // Fused gate matrices M = RZ@RY@RX = [[a,b],[-conj(b),conj(a)]]
  if (t < 36) {
    const float* P = params + t * 3;
    float hx = P[0]*0.5f, hy = P[1]*0.5f, hz = P[2]*0.5f;
    float cx = cosf(hx), sx = sinf(hx);
    float cy = cosf(hy), sy = sinf(hy);
    float cz = cosf(hz), sz = sinf(hz);
    float arr = cy*cx, aii = sy*sx, brr = sy*cx, bii = cy*sx;
    ga4[t] = make_float4(cz*arr + sz*aii,
                         cz*aii - sz*arr,
                         -(cz*brr + sz*bii),
                         -(cz*bii - sz*brr));
  }

  // ---- load 16 consecutive amps + block-wide norm ----
  float re[16], im[16];
  const float* inb = in + (size_t)b * DIM + t * 16;
  float ss = 0.f;
  #pragma unroll
  for (int q = 0; q < 4; ++q) {
    float4 v = reinterpret_cast<const float4*>(inb)[q];
    re[4*q+0]=v.x; re[4*q+1]=v.y; re[4*q+2]=v.z; re[4*q+3]=v.w;
    ss += v.x*v.x + v.y*v.y + v.z*v.z + v.w*v.w;
  }
  #pragma unroll
  for (int o = 1; o < 64; o <<= 1) ss += __shfl_xor(ss, o, 64);
  if ((t & 63) == 0) red[t >> 6] = ss;
  __syncthreads();               // also publishes ga4
  float inv = 1.0f / sqrtf(red[0] + red[1] + red[2] + red[3]);
  #pragma unroll
  for (int j = 0; j < 16; ++j) { re[j] *= inv; im[j] = 0.f; }

  // thread-constant addressing (all GF(2)-linear in i)
  const int wbase = (t << 4) ^ h4(t & 15);          // write slot = wbase ^ j
  const int sig   = (t << 4) ^ (t << 3);            // sigma(i) thread part
  const int sigc  = sig & 1023;                     // bits 11,10 cleared
  const int gb    = sigc ^ h4((sigc >> 4) & 15);    // gather slot = gb ^ g(j) + y*1024
  const int x11   = (t >> 7) & 1;                   // sigma(i) bit 11 (wire 0)
  const int x10   = ((t >> 6) ^ (t >> 7)) & 1;      // sigma(i) bit 10 (wire 1)
  const int paddr = ((t ^ 32) & 63) << 2;           // bpermute addr for mask 32

  for (int L = 0; L < 3; ++L) {
    // ---- 4 register gates: wires 8..11, mask on j ----
    #pragma unroll
    for (int w = 8; w <= 11; ++w) {
      const int m = 1 << (11 - w);
      float4 g = ga4[L*12 + w];
      float ar = g.x, ai = g.y, br = g.z, bi = g.w;
      #pragma unroll
      for (int p = 0; p < 16; ++p) {
        if (!(p & m)) {
          const int k2 = p | m;
          float v0r = re[p], v0i = im[p], v1r = re[k2], v1i = im[k2];
          re[p]  =  ar*v0r - ai*v0i + br*v1r - bi*v1i;
          im[p]  =  ar*v0i + ai*v0r + br*v1i + bi*v1r;
          re[k2] = -br*v0r - bi*v0i + ar*v1r + ai*v1i;
          im[k2] = -br*v0i + bi*v0r + ar*v1i - ai*v1r;
        }
      }
    }
    // ---- 6 lane gates: wires 2..7 -> masks 32,16,8,4,2,1 ----
    lane_gate<32>(ga4[L*12 + 2], t, paddr, re, im);
    lane_gate<16>(ga4[L*12 + 3], t, paddr, re, im);
    lane_gate< 8>(ga4[L*12 + 4], t, paddr, re, im);
    lane_gate< 4>(ga4[L*12 + 5], t, paddr, re, im);
    lane_gate< 2>(ga4[L*12 + 6], t, paddr, re, im);
    lane_gate< 1>(ga4[L*12 + 7], t, paddr, re, im);

    // ---- write post-(wires 2..11) state (conflict-free swizzled) ----
    #pragma unroll
    for (int j = 0; j < 16; ++j) st2[wbase ^ j] = make_float2(re[j], im[j]);
    __syncthreads();

    // ---- fused: wave gates (wires 0,1) + CNOT chain, via 4-partner gather ----
    // new[i] = sum_y G0[x11][y>>1]*G1[x10][y&1] * mid[sigma(i) w/ bits11,10 := y]
    float4 g0 = ga4[L*12 + 0], g1 = ga4[L*12 + 1];
    float u0r, u0i, u1r, u1i, v0r, v0i, v1r, v1i;
    if (x11) { u0r = -g0.z; u0i = g0.w; u1r = g0.x; u1i = -g0.y; }
    else     { u0r =  g0.x; u0i = g0.y; u1r = g0.z; u1i =  g0.w; }
    if (x10) { v0r = -g1.z; v0i = g1.w; v1r = g1.x; v1i = -g1.y; }
    else     { v0r =  g1.x; v0i = g1.y; v1r = g1.z; v1i =  g1.w; }
    float c0r = u0r*v0r - u0i*v0i, c0i = u0r*v0i + u0i*v0r;
    float c1r = u0r*v1r - u0i*v1i, c1i = u0r*v1i + u0i*v1r;
    float c2r = u1r*v0r - u1i*v0i, c2i = u1r*v0i + u1i*v0r;
    float c3r = u1r*v1r - u1i*v1i, c3i = u1r*v1i + u1i*v1r;
    #pragma unroll
    for (int j = 0; j < 16; ++j) {
      const int base = gb ^ (j ^ (j >> 1));
      float2 m0 = st2[base];
      float2 m1 = st2[base + 1024];
      float2 m2 = st2[base + 2048];
      float2 m3 = st2[base + 3072];
      re[j] = c0r*m0.x - c0i*m0.y + c1r*m1.x - c1i*m1.y
            + c2r*m2.x - c2i*m2.y + c3r*m3.x - c3i*m3.y;
      im[j] = c0r*m0.y + c0i*m0.x + c1r*m1.y + c1i*m1.x
            + c2r*m2.y + c2i*m2.x + c3r*m3.y + c3i*m3.x;
    }
    if (L != 2) __syncthreads();  // WAR guard; not needed after last gather
  }

  // ---- readout: sum |amp|^2 * c(i), i = t*16 + j (regs hold final state) ----
  float Ct = 0.f;
  #pragma unroll
  for (int p = 0; p < 8; ++p) Ct += hw[7-p] * (((t >> p) & 1) ? -1.f : 1.f);
  float h11 = hw[11], h10 = hw[10], h9 = hw[9], h8 = hw[8];
  float acc = 0.f;
  #pragma unroll
  for (int j = 0; j < 16; ++j) {
    float pj = re[j]*re[j] + im[j]*im[j];
    float cj = ((j&1) ? -h11 : h11) + ((j&2) ? -h10 : h10)
             + ((j&4) ? -h9  : h9 ) + ((j&8) ? -h8  : h8 );
    acc += pj * (Ct + cj);
  }
  #pragma unroll
  for (int o = 1; o < 64; o <<= 1) acc += __shfl_xor(acc, o, 64);
  if ((t & 63) == 0) red[t >> 6] = acc;
  __syncthreads();
  if (t == 0) out[b] = red[0] + red[1] + red[2] + red[3] + hb[0];
}

extern "C" void kernel_launch(void* const* d_in, const int* in_sizes, int n_in,
                              void* d_out, int out_size, void* d_ws, size_t ws_size,
                              hipStream_t stream) {
  const float* st     = (const float*)d_in[0];
  const float* params = (const float*)d_in[1];
  const float* hwp    = (const float*)d_in[2];
  const float* hbp    = (const float*)d_in[3];
  float* outp = (float*)d_out;
  int batch = in_sizes[0] / DIM;
  qsim_kernel<<<batch, 256, 0, stream>>>(st, params, hwp, hbp, outp);
}